// Round 5
// baseline (160.505 us; speedup 1.0000x reference)
//
#include <hip/hip_runtime.h>
#include <math.h>

#define L_IN 256000
#define T_FR 1601
#define T_PAD 1616
#define NMEL_K 64
#define F_BINS 257
#define HOP_K 160
#define PRE_E 0.97f
#define LOG_GUARD_K 5.9604644775390625e-08f  // 2^-24
#define FPB 16        // frames per block
#define CONC 4        // one frame per wave
#define GROUPS 101    // ceil(1601/16)
#define SPAN 2912     // 160*(FPB-1) + 512

__device__ __forceinline__ float2 cmulf(float2 a, float2 b) {
  return make_float2(a.x * b.x - a.y * b.y, a.x * b.y + a.y * b.x);
}

// Prep: per-mel compact filterbank (32 wide, 16B-aligned, zero-padded) + aligned lo,
// and zero the stats accumulators (ws is poisoned 0xAA before every launch).
__global__ void prep_kernel(const float* __restrict__ fb, float* __restrict__ fbc,
                            int* __restrict__ loAl, float* __restrict__ rsum,
                            float* __restrict__ rsumsq) {
  const int m = blockIdx.x;
  const int t = threadIdx.x;
  if (t < 32) {  // zero stats: 64 blocks x 32 = 2048 each
    rsum[m * 32 + t] = 0.0f;
    rsumsq[m * 32 + t] = 0.0f;
  }
  int first = 512, last = -1;
  for (int c = 0; c < 5; ++c) {
    int f = t + 64 * c;
    if (f < F_BINS) {
      float v = fb[m * F_BINS + f];
      if (v > 0.0f) { first = min(first, f); last = max(last, f); }
    }
  }
  for (int off = 32; off > 0; off >>= 1) {
    first = min(first, __shfl_xor(first, off));
    last = max(last, __shfl_xor(last, off));
  }
  int lo = (first <= last) ? first : 0;
  int lastv = (first <= last) ? last : 0;
  int la = lo & ~3;
  if (t == 0) loAl[m] = la;
  if (t < 32) {
    int f = la + t;
    float v = (f >= lo && f <= lastv && f < F_BINS) ? fb[m * F_BINS + f] : 0.0f;
    fbc[m * 32 + t] = v;
  }
}

// K1: 256 threads = 4 waves, 16 frames per block. Register 4-step FFT (shfl
// butterflies), sparse mel, logmel, PLUS per-(b,mel) sum/sumsq accumulated in
// registers and flushed with 2 atomics per wave at task end.
__global__ void __launch_bounds__(256) frame_fft_mel_kernel(
    const float* __restrict__ x, const int* __restrict__ seq_len,
    const float* __restrict__ window, const float* __restrict__ fbc,
    const int* __restrict__ loAl, float* __restrict__ out,
    float* __restrict__ rsum, float* __restrict__ rsumsq) {
  __shared__ __align__(16) float xs[SPAN];
  __shared__ __align__(16) float pw[CONC][288];
  __shared__ float outm[NMEL_K][FPB + 1];

  const int tid = threadIdx.x;
  const int w = tid >> 6;
  const int lane = tid & 63;
  const int b = blockIdx.x / GROUPS;
  const int g = blockIdx.x - b * GROUPS;
  const int t0 = g * FPB;
  const float* xb = x + (size_t)b * L_IN;
  const int base = t0 * HOP_K - 256;
  const int fl = seq_len[b] / HOP_K + 1;

  // stage input span: preemph (+ reflect on edge blocks)
  if (base >= 0 && base + SPAN <= L_IN) {
    // fast path: float4 interior (base is a multiple of 4 for g>0)
    const float4* xb4 = (const float4*)(xb + base);
    float4* xs4 = (float4*)xs;
    for (int s4 = tid; s4 < SPAN / 4; s4 += 256) {
      float4 cur = xb4[s4];
      float prev = xb[base + 4 * s4 - 1];
      float4 o;
      o.x = fmaf(-PRE_E, prev, cur.x);
      o.y = fmaf(-PRE_E, cur.x, cur.y);
      o.z = fmaf(-PRE_E, cur.y, cur.z);
      o.w = fmaf(-PRE_E, cur.z, cur.w);
      xs4[s4] = o;
    }
  } else {
    for (int n = tid; n < SPAN; n += 256) {
      int i = base + n;
      i = (i < 0) ? -i : i;
      i = (i >= L_IN) ? (2 * L_IN - 2 - i) : i;
      xs[n] = (i == 0) ? xb[0] : fmaf(-PRE_E, xb[i - 1], xb[i]);
    }
  }

  // ---- per-lane frame-invariant constants (all hoisted) ----
  const int sig = __builtin_bitreverse32(lane) >> 26;  // bitrev6(lane)
  float wr[4], wi[4];
#pragma unroll
  for (int q = 0; q < 4; ++q) {
    float2 wv = *(const float2*)(window + 2 * (lane + 64 * q));
    wr[q] = wv.x; wi[q] = wv.y;
  }
  float2 tw1, tw2, tw3;  // W256^(l*r)
  {
    float a = -0.024543692606170259f * (float)lane;  // -2*pi/256
    __sincosf(a, &tw1.y, &tw1.x);
    tw2 = cmulf(tw1, tw1);
    tw3 = cmulf(tw2, tw1);
  }
  float stc[6], sts[6];  // DIF stage twiddles W_{2H}^{lane&(H-1)}
#pragma unroll
  for (int i = 0; i < 6; ++i) {
    int H = 32 >> i;
    int p = lane & (H - 1);
    float a = -3.14159265358979323846f * (float)p / (float)H;
    __sincosf(a, &sts[i], &stc[i]);
  }
  float cu[4], su[4];  // unpack twiddle e^{-i*pi*(4*sig+r)/256}
  {
    float a = -0.049087385212340519f * (float)sig;  // -pi/64
    float cb, sb;
    __sincosf(a, &sb, &cb);
    const float C[4] = {1.0f, 0.99992470183914454f, 0.99969881869620425f, 0.99932238458834954f};
    const float S[4] = {0.0f, 0.01227153828571993f, 0.02454122852291229f, 0.03680722294135883f};
#pragma unroll
    for (int r = 0; r < 4; ++r) {
      cu[r] = cb * C[r] + sb * S[r];
      su[r] = sb * C[r] - cb * S[r];
    }
  }
  const int idx0 = __builtin_bitreverse32((64 - sig) & 63) >> 26;  // lane of Y0[(64-s)&63]
  const int la = loAl[lane];
  const float4* fr4 = (const float4*)fbc + lane * 8;

  __syncthreads();

  float sm = 0.0f, ssq = 0.0f;  // per-(b, mel=lane) stats partials

  for (int c = 0; c < FPB / CONC; ++c) {
    const int j = c * CONC + w;
    const int off = j * HOP_K;

    float Br[4], Bi[4];
    {
      float zr[4], zi[4];
#pragma unroll
      for (int q = 0; q < 4; ++q) {
        float2 v = *(const float2*)(xs + off + 2 * (lane + 64 * q));
        zr[q] = v.x * wr[q];
        zi[q] = v.y * wi[q];
      }
      // FFT_4 over q (W4 = -i), then W256^{l*r} twiddle
      float e0r = zr[0] + zr[2], e0i = zi[0] + zi[2];
      float e1r = zr[1] + zr[3], e1i = zi[1] + zi[3];
      float d0r = zr[0] - zr[2], d0i = zi[0] - zi[2];
      float d1r = zr[1] - zr[3], d1i = zi[1] - zi[3];
      Br[0] = e0r + e1r; Bi[0] = e0i + e1i;
      float A2r = e0r - e1r, A2i = e0i - e1i;
      float A1r = d0r + d1i, A1i = d0i - d1r;
      float A3r = d0r - d1i, A3i = d0i + d1r;
      Br[1] = A1r * tw1.x - A1i * tw1.y; Bi[1] = A1r * tw1.y + A1i * tw1.x;
      Br[2] = A2r * tw2.x - A2i * tw2.y; Bi[2] = A2r * tw2.y + A2i * tw2.x;
      Br[3] = A3r * tw3.x - A3i * tw3.y; Bi[3] = A3r * tw3.y + A3i * tw3.x;
    }

    // FFT_64 across lanes: 6 DIF radix-2 stages, H = 32..1
#pragma unroll
    for (int i = 0; i < 6; ++i) {
      const int H = 32 >> i;
      const bool hi = (lane & H) != 0;
      const float cc = stc[i], ss = sts[i];
#pragma unroll
      for (int r = 0; r < 4; ++r) {
        float tr = __shfl_xor(Br[r], H);
        float ti = __shfl_xor(Bi[r], H);
        float sr = Br[r] + tr, si = Bi[r] + ti;
        float dr = tr - Br[r], di = ti - Bi[r];
        float pr = dr * cc - di * ss, pi = dr * ss + di * cc;
        Br[r] = hi ? pr : sr;
        Bi[r] = hi ? pi : si;
      }
    }

    // packed-real unpack + power spectrum (k = 4*sig + r)
    {
      float q3r = __shfl_xor(Br[3], 63), q3i = __shfl_xor(Bi[3], 63);
      float q2r = __shfl_xor(Br[2], 63), q2i = __shfl_xor(Bi[2], 63);
      float q1r = __shfl_xor(Br[1], 63), q1i = __shfl_xor(Bi[1], 63);
      float q0r = __shfl(Br[0], idx0), q0i = __shfl(Bi[0], idx0);
      float qr[4] = {q0r, q3r, q2r, q1r};
      float qi_[4] = {q0i, q3i, q2i, q1i};
      float pv[4];
#pragma unroll
      for (int r = 0; r < 4; ++r) {
        float Er = 0.5f * (Br[r] + qr[r]);
        float Ei = 0.5f * (Bi[r] - qi_[r]);
        float Or = 0.5f * (Bi[r] + qi_[r]);
        float Oi = 0.5f * (qr[r] - Br[r]);
        float Xr = Er + cu[r] * Or - su[r] * Oi;
        float Xi = Ei + cu[r] * Oi + su[r] * Or;
        pv[r] = Xr * Xr + Xi * Xi;
      }
      ((float4*)pw[w])[sig] = make_float4(pv[0], pv[1], pv[2], pv[3]);
      if (lane == 0) { float d = Br[0] - Bi[0]; pw[w][256] = d * d; }
      else if (lane < 32) pw[w][256 + lane] = 0.0f;  // zero tail for gather overrun
    }
    __builtin_amdgcn_wave_barrier();

    // uniform mel gather: 8 x (global fbc quad, LDS pw quad); lane == mel
    {
      const float4* pq = (const float4*)pw[w] + (la >> 2);
      float acc = 0.0f;
#pragma unroll
      for (int jj = 0; jj < 8; ++jj) {
        float4 wq = fr4[jj];
        float4 p = pq[jj];
        acc = fmaf(wq.x, p.x, acc);
        acc = fmaf(wq.y, p.y, acc);
        acc = fmaf(wq.z, p.z, acc);
        acc = fmaf(wq.w, p.w, acc);
      }
      float lv = __logf(acc + LOG_GUARD_K);
      outm[lane][j] = lv;
      if (t0 + j < fl) { sm += lv; ssq = fmaf(lv, lv, ssq); }
    }
    __builtin_amdgcn_wave_barrier();
  }

  // flush stats: one atomic pair per (wave, mel=lane)
  atomicAdd(&rsum[(b << 6) + lane], sm);
  atomicAdd(&rsumsq[(b << 6) + lane], ssq);

  __syncthreads();
  // coalesced store: 16 consecutive t per mel row
#pragma unroll
  for (int p = 0; p < 4; ++p) {
    int row = p * 16 + (tid >> 4);
    int jj = tid & 15;
    int t = t0 + jj;
    if (t < T_FR)
      out[((size_t)(b << 6) + row) * T_PAD + t] = outm[row][jj];
  }
}

// K2: pure elementwise normalize (stats precomputed by K1) + feat_len write.
__global__ void __launch_bounds__(256) norm_elem_kernel(
    const int* __restrict__ seq_len, const float* __restrict__ rsum,
    const float* __restrict__ rsumsq, float* __restrict__ out,
    float* __restrict__ fl_out) {
  const int cidx = blockIdx.x * 256 + threadIdx.x;  // float4 chunk index
  const int bm = cidx / (T_PAD / 4);
  const int c4 = cidx - bm * (T_PAD / 4);
  const int b = bm >> 6;
  const int fl = seq_len[b] / HOP_K + 1;
  const float n = (float)fl;
  float s = rsum[bm], ssq = rsumsq[bm];
  float mean = s / n;
  float var = (ssq - s * mean) / (n - 1.0f);
  float istd = 1.0f / (sqrtf(var) + 1e-5f);
  float4* rowp = (float4*)(out + (size_t)bm * T_PAD);
  float4 v = rowp[c4];
  int t = 4 * c4;
  float4 o;
  o.x = (t < fl) ? (v.x - mean) * istd : 0.0f;
  o.y = (t + 1 < fl) ? (v.y - mean) * istd : 0.0f;
  o.z = (t + 2 < fl) ? (v.z - mean) * istd : 0.0f;
  o.w = (t + 3 < fl) ? (v.w - mean) * istd : 0.0f;
  rowp[c4] = o;
  if (blockIdx.x == 0 && threadIdx.x < 32)
    fl_out[threadIdx.x] = (float)(seq_len[threadIdx.x] / HOP_K + 1);
}

extern "C" void kernel_launch(void* const* d_in, const int* in_sizes, int n_in,
                              void* d_out, int out_size, void* d_ws, size_t ws_size,
                              hipStream_t stream) {
  const float* x = (const float*)d_in[0];
  const int* seq_len = (const int*)d_in[1];
  const float* window = (const float*)d_in[2];
  const float* fb = (const float*)d_in[3];
  float* out = (float*)d_out;
  float* fl_out = out + (size_t)32 * NMEL_K * T_PAD;
  float* fbc = (float*)d_ws;                          // 2048 floats
  int* loAl = (int*)((char*)d_ws + 8192);             // 64 ints
  float* rsum = (float*)((char*)d_ws + 8448);         // 2048 floats
  float* rsumsq = (float*)((char*)d_ws + 16640);      // 2048 floats

  prep_kernel<<<NMEL_K, 64, 0, stream>>>(fb, fbc, loAl, rsum, rsumsq);
  frame_fft_mel_kernel<<<32 * GROUPS, 256, 0, stream>>>(x, seq_len, window, fbc,
                                                        loAl, out, rsum, rsumsq);
  norm_elem_kernel<<<(32 * NMEL_K * T_PAD / 4) / 256, 256, 0, stream>>>(
      seq_len, rsum, rsumsq, out, fl_out);
}

// Round 6
// 134.190 us; speedup vs baseline: 1.1961x; 1.1961x over previous
//
#include <hip/hip_runtime.h>
#include <math.h>

#define L_IN 256000
#define T_FR 1601
#define T_PAD 1616
#define NMEL_K 64
#define F_BINS 257
#define HOP_K 160
#define PRE_E 0.97f
#define LOG_GUARD_K 5.9604644775390625e-08f  // 2^-24
#define FPB 16        // frames per block
#define CONC 4        // one frame per wave
#define GROUPS 101    // ceil(1601/16)
#define SPAN 2912     // 160*(FPB-1) + 512

__device__ __forceinline__ float2 cmulf(float2 a, float2 b) {
  return make_float2(a.x * b.x - a.y * b.y, a.x * b.y + a.y * b.x);
}

// Prep: per-mel compact filterbank (32 wide, 16B-aligned, zero-padded) + aligned lo,
// and zero the stats accumulators (ws is poisoned 0xAA before every launch).
__global__ void prep_kernel(const float* __restrict__ fb, float* __restrict__ fbc,
                            int* __restrict__ loAl, float* __restrict__ rsum,
                            float* __restrict__ rsumsq) {
  const int m = blockIdx.x;
  const int t = threadIdx.x;
  if (t < 32) {  // zero stats: 64 blocks x 32 = 2048 each
    rsum[m * 32 + t] = 0.0f;
    rsumsq[m * 32 + t] = 0.0f;
  }
  int first = 512, last = -1;
  for (int c = 0; c < 5; ++c) {
    int f = t + 64 * c;
    if (f < F_BINS) {
      float v = fb[m * F_BINS + f];
      if (v > 0.0f) { first = min(first, f); last = max(last, f); }
    }
  }
  for (int off = 32; off > 0; off >>= 1) {
    first = min(first, __shfl_xor(first, off));
    last = max(last, __shfl_xor(last, off));
  }
  int lo = (first <= last) ? first : 0;
  int lastv = (first <= last) ? last : 0;
  int la = lo & ~3;
  if (t == 0) loAl[m] = la;
  if (t < 32) {
    int f = la + t;
    float v = (f >= lo && f <= lastv && f < F_BINS) ? fb[m * F_BINS + f] : 0.0f;
    fbc[m * 32 + t] = v;
  }
}

// K1: 256 threads = 4 waves, 16 frames per block. Register 4-step FFT (shfl
// butterflies), sparse mel, logmel. Stats sum/sumsq accumulated in registers,
// cross-wave reduced in LDS, flushed with 128 fire-and-forget atomics per block
// AFTER the output stores (no barrier after atomics — avoids the vmcnt(0)
// drain-before-s_barrier stall that cost 19 us in R5).
__global__ void __launch_bounds__(256) frame_fft_mel_kernel(
    const float* __restrict__ x, const int* __restrict__ seq_len,
    const float* __restrict__ window, const float* __restrict__ fbc,
    const int* __restrict__ loAl, float* __restrict__ out,
    float* __restrict__ rsum, float* __restrict__ rsumsq) {
  __shared__ __align__(16) float xs[SPAN];
  __shared__ __align__(16) float pw[CONC][288];
  __shared__ float outm[NMEL_K][FPB + 1];

  const int tid = threadIdx.x;
  const int w = tid >> 6;
  const int lane = tid & 63;
  const int b = blockIdx.x / GROUPS;
  const int g = blockIdx.x - b * GROUPS;
  const int t0 = g * FPB;
  const float* xb = x + (size_t)b * L_IN;
  const int base = t0 * HOP_K - 256;
  const int fl = seq_len[b] / HOP_K + 1;

  // stage input span: preemph (+ reflect on edge blocks)
  if (base >= 0 && base + SPAN <= L_IN) {
    // fast path: float4 interior (base is a multiple of 4 for g>0)
    const float4* xb4 = (const float4*)(xb + base);
    float4* xs4 = (float4*)xs;
    for (int s4 = tid; s4 < SPAN / 4; s4 += 256) {
      float4 cur = xb4[s4];
      float prev = xb[base + 4 * s4 - 1];
      float4 o;
      o.x = fmaf(-PRE_E, prev, cur.x);
      o.y = fmaf(-PRE_E, cur.x, cur.y);
      o.z = fmaf(-PRE_E, cur.y, cur.z);
      o.w = fmaf(-PRE_E, cur.z, cur.w);
      xs4[s4] = o;
    }
  } else {
    for (int n = tid; n < SPAN; n += 256) {
      int i = base + n;
      i = (i < 0) ? -i : i;
      i = (i >= L_IN) ? (2 * L_IN - 2 - i) : i;
      xs[n] = (i == 0) ? xb[0] : fmaf(-PRE_E, xb[i - 1], xb[i]);
    }
  }

  // ---- per-lane frame-invariant constants (all hoisted) ----
  const int sig = __builtin_bitreverse32(lane) >> 26;  // bitrev6(lane)
  float wr[4], wi[4];
#pragma unroll
  for (int q = 0; q < 4; ++q) {
    float2 wv = *(const float2*)(window + 2 * (lane + 64 * q));
    wr[q] = wv.x; wi[q] = wv.y;
  }
  float2 tw1, tw2, tw3;  // W256^(l*r)
  {
    float a = -0.024543692606170259f * (float)lane;  // -2*pi/256
    __sincosf(a, &tw1.y, &tw1.x);
    tw2 = cmulf(tw1, tw1);
    tw3 = cmulf(tw2, tw1);
  }
  float stc[6], sts[6];  // DIF stage twiddles W_{2H}^{lane&(H-1)}
#pragma unroll
  for (int i = 0; i < 6; ++i) {
    int H = 32 >> i;
    int p = lane & (H - 1);
    float a = -3.14159265358979323846f * (float)p / (float)H;
    __sincosf(a, &sts[i], &stc[i]);
  }
  float cu[4], su[4];  // unpack twiddle e^{-i*pi*(4*sig+r)/256}
  {
    float a = -0.049087385212340519f * (float)sig;  // -pi/64
    float cb, sb;
    __sincosf(a, &sb, &cb);
    const float C[4] = {1.0f, 0.99992470183914454f, 0.99969881869620425f, 0.99932238458834954f};
    const float S[4] = {0.0f, 0.01227153828571993f, 0.02454122852291229f, 0.03680722294135883f};
#pragma unroll
    for (int r = 0; r < 4; ++r) {
      cu[r] = cb * C[r] + sb * S[r];
      su[r] = sb * C[r] - cb * S[r];
    }
  }
  const int idx0 = __builtin_bitreverse32((64 - sig) & 63) >> 26;  // lane of Y0[(64-s)&63]
  const int la = loAl[lane];
  const float4* fr4 = (const float4*)fbc + lane * 8;

  __syncthreads();

  float sm = 0.0f, ssq = 0.0f;  // per-(b, mel=lane) stats partials

  for (int c = 0; c < FPB / CONC; ++c) {
    const int j = c * CONC + w;
    const int off = j * HOP_K;

    float Br[4], Bi[4];
    {
      float zr[4], zi[4];
#pragma unroll
      for (int q = 0; q < 4; ++q) {
        float2 v = *(const float2*)(xs + off + 2 * (lane + 64 * q));
        zr[q] = v.x * wr[q];
        zi[q] = v.y * wi[q];
      }
      // FFT_4 over q (W4 = -i), then W256^{l*r} twiddle
      float e0r = zr[0] + zr[2], e0i = zi[0] + zi[2];
      float e1r = zr[1] + zr[3], e1i = zi[1] + zi[3];
      float d0r = zr[0] - zr[2], d0i = zi[0] - zi[2];
      float d1r = zr[1] - zr[3], d1i = zi[1] - zi[3];
      Br[0] = e0r + e1r; Bi[0] = e0i + e1i;
      float A2r = e0r - e1r, A2i = e0i - e1i;
      float A1r = d0r + d1i, A1i = d0i - d1r;
      float A3r = d0r - d1i, A3i = d0i + d1r;
      Br[1] = A1r * tw1.x - A1i * tw1.y; Bi[1] = A1r * tw1.y + A1i * tw1.x;
      Br[2] = A2r * tw2.x - A2i * tw2.y; Bi[2] = A2r * tw2.y + A2i * tw2.x;
      Br[3] = A3r * tw3.x - A3i * tw3.y; Bi[3] = A3r * tw3.y + A3i * tw3.x;
    }

    // FFT_64 across lanes: 6 DIF radix-2 stages, H = 32..1
#pragma unroll
    for (int i = 0; i < 6; ++i) {
      const int H = 32 >> i;
      const bool hi = (lane & H) != 0;
      const float cc = stc[i], ss = sts[i];
#pragma unroll
      for (int r = 0; r < 4; ++r) {
        float tr = __shfl_xor(Br[r], H);
        float ti = __shfl_xor(Bi[r], H);
        float sr = Br[r] + tr, si = Bi[r] + ti;
        float dr = tr - Br[r], di = ti - Bi[r];
        float pr = dr * cc - di * ss, pi = dr * ss + di * cc;
        Br[r] = hi ? pr : sr;
        Bi[r] = hi ? pi : si;
      }
    }

    // packed-real unpack + power spectrum (k = 4*sig + r)
    {
      float q3r = __shfl_xor(Br[3], 63), q3i = __shfl_xor(Bi[3], 63);
      float q2r = __shfl_xor(Br[2], 63), q2i = __shfl_xor(Bi[2], 63);
      float q1r = __shfl_xor(Br[1], 63), q1i = __shfl_xor(Bi[1], 63);
      float q0r = __shfl(Br[0], idx0), q0i = __shfl(Bi[0], idx0);
      float qr[4] = {q0r, q3r, q2r, q1r};
      float qi_[4] = {q0i, q3i, q2i, q1i};
      float pv[4];
#pragma unroll
      for (int r = 0; r < 4; ++r) {
        float Er = 0.5f * (Br[r] + qr[r]);
        float Ei = 0.5f * (Bi[r] - qi_[r]);
        float Or = 0.5f * (Bi[r] + qi_[r]);
        float Oi = 0.5f * (qr[r] - Br[r]);
        float Xr = Er + cu[r] * Or - su[r] * Oi;
        float Xi = Ei + cu[r] * Oi + su[r] * Or;
        pv[r] = Xr * Xr + Xi * Xi;
      }
      ((float4*)pw[w])[sig] = make_float4(pv[0], pv[1], pv[2], pv[3]);
      if (lane == 0) { float d = Br[0] - Bi[0]; pw[w][256] = d * d; }
      else if (lane < 32) pw[w][256 + lane] = 0.0f;  // zero tail for gather overrun
    }
    __builtin_amdgcn_wave_barrier();

    // uniform mel gather: 8 x (global fbc quad, LDS pw quad); lane == mel
    {
      const float4* pq = (const float4*)pw[w] + (la >> 2);
      float acc = 0.0f;
#pragma unroll
      for (int jj = 0; jj < 8; ++jj) {
        float4 wq = fr4[jj];
        float4 p = pq[jj];
        acc = fmaf(wq.x, p.x, acc);
        acc = fmaf(wq.y, p.y, acc);
        acc = fmaf(wq.z, p.z, acc);
        acc = fmaf(wq.w, p.w, acc);
      }
      float lv = __logf(acc + LOG_GUARD_K);
      outm[lane][j] = lv;
      if (t0 + j < fl) { sm += lv; ssq = fmaf(lv, lv, ssq); }
    }
    __builtin_amdgcn_wave_barrier();
  }

  // park per-wave stats partials in pw scratch (mel loop done, pw is free)
  pw[w][lane] = sm;
  pw[w][64 + lane] = ssq;

  __syncthreads();

  // coalesced store: 16 consecutive t per mel row
#pragma unroll
  for (int p = 0; p < 4; ++p) {
    int row = p * 16 + (tid >> 4);
    int jj = tid & 15;
    int t = t0 + jj;
    if (t < T_FR)
      out[((size_t)(b << 6) + row) * T_PAD + t] = outm[row][jj];
  }

  // cross-wave reduce + fire-and-forget flush: 128 atomics/block, LAST ops,
  // no trailing barrier (drain overlaps with block retirement)
  if (tid < 64) {
    float s0 = pw[0][tid] + pw[1][tid] + pw[2][tid] + pw[3][tid];
    float q0 = pw[0][64 + tid] + pw[1][64 + tid] + pw[2][64 + tid] + pw[3][64 + tid];
    atomicAdd(&rsum[(b << 6) + tid], s0);
    atomicAdd(&rsumsq[(b << 6) + tid], q0);
  }
}

// K2: pure elementwise normalize (stats precomputed by K1) + feat_len write.
__global__ void __launch_bounds__(256) norm_elem_kernel(
    const int* __restrict__ seq_len, const float* __restrict__ rsum,
    const float* __restrict__ rsumsq, float* __restrict__ out,
    float* __restrict__ fl_out) {
  const int cidx = blockIdx.x * 256 + threadIdx.x;  // float4 chunk index
  const int bm = cidx / (T_PAD / 4);
  const int c4 = cidx - bm * (T_PAD / 4);
  const int b = bm >> 6;
  const int fl = seq_len[b] / HOP_K + 1;
  const float n = (float)fl;
  float s = rsum[bm], ssq = rsumsq[bm];
  float mean = s / n;
  float var = (ssq - s * mean) / (n - 1.0f);
  float istd = 1.0f / (sqrtf(var) + 1e-5f);
  float4* rowp = (float4*)(out + (size_t)bm * T_PAD);
  float4 v = rowp[c4];
  int t = 4 * c4;
  float4 o;
  o.x = (t < fl) ? (v.x - mean) * istd : 0.0f;
  o.y = (t + 1 < fl) ? (v.y - mean) * istd : 0.0f;
  o.z = (t + 2 < fl) ? (v.z - mean) * istd : 0.0f;
  o.w = (t + 3 < fl) ? (v.w - mean) * istd : 0.0f;
  rowp[c4] = o;
  if (blockIdx.x == 0 && threadIdx.x < 32)
    fl_out[threadIdx.x] = (float)(seq_len[threadIdx.x] / HOP_K + 1);
}

extern "C" void kernel_launch(void* const* d_in, const int* in_sizes, int n_in,
                              void* d_out, int out_size, void* d_ws, size_t ws_size,
                              hipStream_t stream) {
  const float* x = (const float*)d_in[0];
  const int* seq_len = (const int*)d_in[1];
  const float* window = (const float*)d_in[2];
  const float* fb = (const float*)d_in[3];
  float* out = (float*)d_out;
  float* fl_out = out + (size_t)32 * NMEL_K * T_PAD;
  float* fbc = (float*)d_ws;                          // 2048 floats
  int* loAl = (int*)((char*)d_ws + 8192);             // 64 ints
  float* rsum = (float*)((char*)d_ws + 8448);         // 2048 floats
  float* rsumsq = (float*)((char*)d_ws + 16640);      // 2048 floats

  prep_kernel<<<NMEL_K, 64, 0, stream>>>(fb, fbc, loAl, rsum, rsumsq);
  frame_fft_mel_kernel<<<32 * GROUPS, 256, 0, stream>>>(x, seq_len, window, fbc,
                                                        loAl, out, rsum, rsumsq);
  norm_elem_kernel<<<(32 * NMEL_K * T_PAD / 4) / 256, 256, 0, stream>>>(
      seq_len, rsum, rsumsq, out, fl_out);
}

// Round 7
// 126.169 us; speedup vs baseline: 1.2721x; 1.0636x over previous
//
#include <hip/hip_runtime.h>
#include <math.h>

#define L_IN 256000
#define T_FR 1601
#define T_PAD 1616
#define NMEL_K 64
#define F_BINS 257
#define HOP_K 160
#define PRE_E 0.97f
#define LOG_GUARD_K 5.9604644775390625e-08f  // 2^-24
#define FPB 16        // frames per block
#define CONC 4        // one frame per wave
#define GROUPS 101    // ceil(1601/16)
#define SPAN 2912     // 160*(FPB-1) + 512

__device__ __forceinline__ float2 cmulf(float2 a, float2 b) {
  return make_float2(a.x * b.x - a.y * b.y, a.x * b.y + a.y * b.x);
}

// quad_perm DPP lane exchanges (VALU pipe — no DS cost).
// xor1: perm [1,0,3,2] = 0xB1; xor2: perm [2,3,0,1] = 0x4E.
__device__ __forceinline__ float dpp_xor1(float x) {
  return __int_as_float(__builtin_amdgcn_mov_dpp(__float_as_int(x), 0xB1, 0xF, 0xF, true));
}
__device__ __forceinline__ float dpp_xor2(float x) {
  return __int_as_float(__builtin_amdgcn_mov_dpp(__float_as_int(x), 0x4E, 0xF, 0xF, true));
}

// Prep: per-mel compact filterbank (32 wide, 16B-aligned, zero-padded) + aligned lo,
// and zero the stats accumulators (ws is poisoned 0xAA before every launch).
__global__ void prep_kernel(const float* __restrict__ fb, float* __restrict__ fbc,
                            int* __restrict__ loAl, float* __restrict__ rsum,
                            float* __restrict__ rsumsq) {
  const int m = blockIdx.x;
  const int t = threadIdx.x;
  if (t < 32) {  // zero stats: 64 blocks x 32 = 2048 each
    rsum[m * 32 + t] = 0.0f;
    rsumsq[m * 32 + t] = 0.0f;
  }
  int first = 512, last = -1;
  for (int c = 0; c < 5; ++c) {
    int f = t + 64 * c;
    if (f < F_BINS) {
      float v = fb[m * F_BINS + f];
      if (v > 0.0f) { first = min(first, f); last = max(last, f); }
    }
  }
  for (int off = 32; off > 0; off >>= 1) {
    first = min(first, __shfl_xor(first, off));
    last = max(last, __shfl_xor(last, off));
  }
  int lo = (first <= last) ? first : 0;
  int lastv = (first <= last) ? last : 0;
  int la = lo & ~3;
  if (t == 0) loAl[m] = la;
  if (t < 32) {
    int f = la + t;
    float v = (f >= lo && f <= lastv && f < F_BINS) ? fb[m * F_BINS + f] : 0.0f;
    fbc[m * 32 + t] = v;
  }
}

// Butterfly stage macro: partner expressions are per-register r.
#define FFT_STAGE(I, PR, PI)                                        \
  {                                                                 \
    const int H__ = 32 >> (I);                                      \
    const bool hi__ = (lane & H__) != 0;                            \
    const float cc__ = stc[I], ss__ = sts[I];                       \
    _Pragma("unroll")                                               \
    for (int r = 0; r < 4; ++r) {                                   \
      float tr = (PR), ti = (PI);                                   \
      float sr = Br[r] + tr, si = Bi[r] + ti;                       \
      float dr = tr - Br[r], di = ti - Bi[r];                       \
      float pr = dr * cc__ - di * ss__, pi = dr * ss__ + di * cc__; \
      Br[r] = hi__ ? pr : sr;                                       \
      Bi[r] = hi__ ? pi : si;                                       \
    }                                                               \
  }

// K1: 256 threads = 4 waves, 16 frames per block. Register 4-step FFT:
// stages H=32..4 via __shfl_xor (DS bpermute), H=2,1 via DPP quad_perm (VALU).
// Sparse mel, logmel, fused per-(b,mel) stats with fire-and-forget atomics.
__global__ void __launch_bounds__(256) frame_fft_mel_kernel(
    const float* __restrict__ x, const int* __restrict__ seq_len,
    const float* __restrict__ window, const float* __restrict__ fbc,
    const int* __restrict__ loAl, float* __restrict__ out,
    float* __restrict__ rsum, float* __restrict__ rsumsq) {
  __shared__ __align__(16) float xs[SPAN];
  __shared__ __align__(16) float pw[CONC][288];
  __shared__ float outm[NMEL_K][FPB + 1];

  const int tid = threadIdx.x;
  const int w = tid >> 6;
  const int lane = tid & 63;
  const int b = blockIdx.x / GROUPS;
  const int g = blockIdx.x - b * GROUPS;
  const int t0 = g * FPB;
  const float* xb = x + (size_t)b * L_IN;
  const int base = t0 * HOP_K - 256;
  const int fl = seq_len[b] / HOP_K + 1;

  // stage input span: preemph (+ reflect on edge blocks)
  if (base >= 0 && base + SPAN <= L_IN) {
    // fast path: float4 interior (base is a multiple of 4 for g>0)
    const float4* xb4 = (const float4*)(xb + base);
    float4* xs4 = (float4*)xs;
    for (int s4 = tid; s4 < SPAN / 4; s4 += 256) {
      float4 cur = xb4[s4];
      float prev = xb[base + 4 * s4 - 1];
      float4 o;
      o.x = fmaf(-PRE_E, prev, cur.x);
      o.y = fmaf(-PRE_E, cur.x, cur.y);
      o.z = fmaf(-PRE_E, cur.y, cur.z);
      o.w = fmaf(-PRE_E, cur.z, cur.w);
      xs4[s4] = o;
    }
  } else {
    for (int n = tid; n < SPAN; n += 256) {
      int i = base + n;
      i = (i < 0) ? -i : i;
      i = (i >= L_IN) ? (2 * L_IN - 2 - i) : i;
      xs[n] = (i == 0) ? xb[0] : fmaf(-PRE_E, xb[i - 1], xb[i]);
    }
  }

  // zero pw tail once (gather overrun region 257..287 — never overwritten)
  if (lane >= 33 && lane < 64) pw[w][224 + lane] = 0.0f;  // 257..287

  // ---- per-lane frame-invariant constants (all hoisted) ----
  const int sig = __builtin_bitreverse32(lane) >> 26;  // bitrev6(lane)
  float wr[4], wi[4];
#pragma unroll
  for (int q = 0; q < 4; ++q) {
    float2 wv = *(const float2*)(window + 2 * (lane + 64 * q));
    wr[q] = wv.x; wi[q] = wv.y;
  }
  float2 tw1, tw2, tw3;  // W256^(l*r)
  {
    float a = -0.024543692606170259f * (float)lane;  // -2*pi/256
    __sincosf(a, &tw1.y, &tw1.x);
    tw2 = cmulf(tw1, tw1);
    tw3 = cmulf(tw2, tw1);
  }
  float stc[6], sts[6];  // DIF stage twiddles W_{2H}^{lane&(H-1)}
#pragma unroll
  for (int i = 0; i < 6; ++i) {
    int H = 32 >> i;
    int p = lane & (H - 1);
    float a = -3.14159265358979323846f * (float)p / (float)H;
    __sincosf(a, &sts[i], &stc[i]);
  }
  float cu[4], su[4];  // unpack twiddle e^{-i*pi*(4*sig+r)/256}
  {
    float a = -0.049087385212340519f * (float)sig;  // -pi/64
    float cb, sb;
    __sincosf(a, &sb, &cb);
    const float C[4] = {1.0f, 0.99992470183914454f, 0.99969881869620425f, 0.99932238458834954f};
    const float S[4] = {0.0f, 0.01227153828571993f, 0.02454122852291229f, 0.03680722294135883f};
#pragma unroll
    for (int r = 0; r < 4; ++r) {
      cu[r] = cb * C[r] + sb * S[r];
      su[r] = sb * C[r] - cb * S[r];
    }
  }
  const int idx0 = __builtin_bitreverse32((64 - sig) & 63) >> 26;  // lane of Y0[(64-s)&63]
  const int la = loAl[lane];
  const float4* fr4 = (const float4*)fbc + lane * 8;

  __syncthreads();

  float sm = 0.0f, ssq = 0.0f;  // per-(b, mel=lane) stats partials

  for (int c = 0; c < FPB / CONC; ++c) {
    const int j = c * CONC + w;
    const int off = j * HOP_K;

    float Br[4], Bi[4];
    {
      float zr[4], zi[4];
#pragma unroll
      for (int q = 0; q < 4; ++q) {
        float2 v = *(const float2*)(xs + off + 2 * (lane + 64 * q));
        zr[q] = v.x * wr[q];
        zi[q] = v.y * wi[q];
      }
      // FFT_4 over q (W4 = -i), then W256^{l*r} twiddle
      float e0r = zr[0] + zr[2], e0i = zi[0] + zi[2];
      float e1r = zr[1] + zr[3], e1i = zi[1] + zi[3];
      float d0r = zr[0] - zr[2], d0i = zi[0] - zi[2];
      float d1r = zr[1] - zr[3], d1i = zi[1] - zi[3];
      Br[0] = e0r + e1r; Bi[0] = e0i + e1i;
      float A2r = e0r - e1r, A2i = e0i - e1i;
      float A1r = d0r + d1i, A1i = d0i - d1r;
      float A3r = d0r - d1i, A3i = d0i + d1r;
      Br[1] = A1r * tw1.x - A1i * tw1.y; Bi[1] = A1r * tw1.y + A1i * tw1.x;
      Br[2] = A2r * tw2.x - A2i * tw2.y; Bi[2] = A2r * tw2.y + A2i * tw2.x;
      Br[3] = A3r * tw3.x - A3i * tw3.y; Bi[3] = A3r * tw3.y + A3i * tw3.x;
    }

    // FFT_64 across lanes: 6 DIF radix-2 stages.
    // H=32..4 via shfl_xor (DS bpermute); H=2,1 via DPP quad_perm (VALU pipe).
    FFT_STAGE(0, __shfl_xor(Br[r], 32), __shfl_xor(Bi[r], 32));
    FFT_STAGE(1, __shfl_xor(Br[r], 16), __shfl_xor(Bi[r], 16));
    FFT_STAGE(2, __shfl_xor(Br[r], 8), __shfl_xor(Bi[r], 8));
    FFT_STAGE(3, __shfl_xor(Br[r], 4), __shfl_xor(Bi[r], 4));
    FFT_STAGE(4, dpp_xor2(Br[r]), dpp_xor2(Bi[r]));
    FFT_STAGE(5, dpp_xor1(Br[r]), dpp_xor1(Bi[r]));

    // packed-real unpack + power spectrum (k = 4*sig + r)
    {
      float q3r = __shfl_xor(Br[3], 63), q3i = __shfl_xor(Bi[3], 63);
      float q2r = __shfl_xor(Br[2], 63), q2i = __shfl_xor(Bi[2], 63);
      float q1r = __shfl_xor(Br[1], 63), q1i = __shfl_xor(Bi[1], 63);
      float q0r = __shfl(Br[0], idx0), q0i = __shfl(Bi[0], idx0);
      float qr[4] = {q0r, q3r, q2r, q1r};
      float qi_[4] = {q0i, q3i, q2i, q1i};
      float pv[4];
#pragma unroll
      for (int r = 0; r < 4; ++r) {
        float Er = 0.5f * (Br[r] + qr[r]);
        float Ei = 0.5f * (Bi[r] - qi_[r]);
        float Or = 0.5f * (Bi[r] + qi_[r]);
        float Oi = 0.5f * (qr[r] - Br[r]);
        float Xr = Er + cu[r] * Or - su[r] * Oi;
        float Xi = Ei + cu[r] * Oi + su[r] * Or;
        pv[r] = Xr * Xr + Xi * Xi;
      }
      ((float4*)pw[w])[sig] = make_float4(pv[0], pv[1], pv[2], pv[3]);
      if (lane == 0) { float d = Br[0] - Bi[0]; pw[w][256] = d * d; }
    }
    __builtin_amdgcn_wave_barrier();

    // uniform mel gather: 8 x (global fbc quad, LDS pw quad); lane == mel
    {
      const float4* pq = (const float4*)pw[w] + (la >> 2);
      float acc = 0.0f;
#pragma unroll
      for (int jj = 0; jj < 8; ++jj) {
        float4 wq = fr4[jj];
        float4 p = pq[jj];
        acc = fmaf(wq.x, p.x, acc);
        acc = fmaf(wq.y, p.y, acc);
        acc = fmaf(wq.z, p.z, acc);
        acc = fmaf(wq.w, p.w, acc);
      }
      float lv = __logf(acc + LOG_GUARD_K);
      outm[lane][j] = lv;
      if (t0 + j < fl) { sm += lv; ssq = fmaf(lv, lv, ssq); }
    }
    __builtin_amdgcn_wave_barrier();
  }

  // park per-wave stats partials in pw scratch (mel loop done, pw is free)
  pw[w][lane] = sm;
  pw[w][64 + lane] = ssq;

  __syncthreads();

  // coalesced store: 16 consecutive t per mel row
#pragma unroll
  for (int p = 0; p < 4; ++p) {
    int row = p * 16 + (tid >> 4);
    int jj = tid & 15;
    int t = t0 + jj;
    if (t < T_FR)
      out[((size_t)(b << 6) + row) * T_PAD + t] = outm[row][jj];
  }

  // cross-wave reduce + fire-and-forget flush: 128 atomics/block, LAST ops,
  // no trailing barrier (drain overlaps with block retirement)
  if (tid < 64) {
    float s0 = pw[0][tid] + pw[1][tid] + pw[2][tid] + pw[3][tid];
    float q0 = pw[0][64 + tid] + pw[1][64 + tid] + pw[2][64 + tid] + pw[3][64 + tid];
    atomicAdd(&rsum[(b << 6) + tid], s0);
    atomicAdd(&rsumsq[(b << 6) + tid], q0);
  }
}

// K2: pure elementwise normalize (stats precomputed by K1) + feat_len write.
__global__ void __launch_bounds__(256) norm_elem_kernel(
    const int* __restrict__ seq_len, const float* __restrict__ rsum,
    const float* __restrict__ rsumsq, float* __restrict__ out,
    float* __restrict__ fl_out) {
  const int cidx = blockIdx.x * 256 + threadIdx.x;  // float4 chunk index
  const int bm = cidx / (T_PAD / 4);
  const int c4 = cidx - bm * (T_PAD / 4);
  const int b = bm >> 6;
  const int fl = seq_len[b] / HOP_K + 1;
  const float n = (float)fl;
  float s = rsum[bm], ssq = rsumsq[bm];
  float mean = s / n;
  float var = (ssq - s * mean) / (n - 1.0f);
  float istd = 1.0f / (sqrtf(var) + 1e-5f);
  float4* rowp = (float4*)(out + (size_t)bm * T_PAD);
  float4 v = rowp[c4];
  int t = 4 * c4;
  float4 o;
  o.x = (t < fl) ? (v.x - mean) * istd : 0.0f;
  o.y = (t + 1 < fl) ? (v.y - mean) * istd : 0.0f;
  o.z = (t + 2 < fl) ? (v.z - mean) * istd : 0.0f;
  o.w = (t + 3 < fl) ? (v.w - mean) * istd : 0.0f;
  rowp[c4] = o;
  if (blockIdx.x == 0 && threadIdx.x < 32)
    fl_out[threadIdx.x] = (float)(seq_len[threadIdx.x] / HOP_K + 1);
}

extern "C" void kernel_launch(void* const* d_in, const int* in_sizes, int n_in,
                              void* d_out, int out_size, void* d_ws, size_t ws_size,
                              hipStream_t stream) {
  const float* x = (const float*)d_in[0];
  const int* seq_len = (const int*)d_in[1];
  const float* window = (const float*)d_in[2];
  const float* fb = (const float*)d_in[3];
  float* out = (float*)d_out;
  float* fl_out = out + (size_t)32 * NMEL_K * T_PAD;
  float* fbc = (float*)d_ws;                          // 2048 floats
  int* loAl = (int*)((char*)d_ws + 8192);             // 64 ints
  float* rsum = (float*)((char*)d_ws + 8448);         // 2048 floats
  float* rsumsq = (float*)((char*)d_ws + 16640);      // 2048 floats

  prep_kernel<<<NMEL_K, 64, 0, stream>>>(fb, fbc, loAl, rsum, rsumsq);
  frame_fft_mel_kernel<<<32 * GROUPS, 256, 0, stream>>>(x, seq_len, window, fbc,
                                                        loAl, out, rsum, rsumsq);
  norm_elem_kernel<<<(32 * NMEL_K * T_PAD / 4) / 256, 256, 0, stream>>>(
      seq_len, rsum, rsumsq, out, fl_out);
}